// Round 1
// baseline (121.640 us; speedup 1.0000x reference)
//
#include <hip/hip_runtime.h>
#include <hip/hip_bf16.h>

#define N_NODES 100000
#define N_EDGES 1600000
#define K_DIM 128
#define N_DIM 128
#define BM_WORDS 3125        // ceil(100000/32)
#define PART_STRIDE 3136     // per-block partial-mask stride, 64B-multiple
#define FLAG_BLOCKS 256
#define PART_OFF 4096        // word offset of partials in d_ws
#define BROWS 128            // rows per gemm block
#define LDA 136              // shorts per LDS row: 272B stride, 16B-aligned, banks +4/row

typedef __attribute__((ext_vector_type(8))) short bf16x8;   // 8 bf16 = 4 VGPRs
typedef __attribute__((ext_vector_type(4))) float f32x4;    // MFMA accumulator

__device__ inline unsigned short f2bf(float f) {
    __hip_bfloat16 b = __float2bfloat16(f);
    return __builtin_bit_cast(unsigned short, b);
}

// Phase A: per-block private bitmask in LDS (LDS atomics only), written to a
// DISJOINT partial-mask region with plain coalesced stores. Zero global
// atomics -> no hot-line serialization at the LLC.
__global__ __launch_bounds__(256)
void flag_partial(const int* __restrict__ ei, unsigned int* __restrict__ parts) {
    __shared__ unsigned int lbm[BM_WORDS];
    for (int i = threadIdx.x; i < BM_WORDS; i += 256) lbm[i] = 0;
    __syncthreads();

    // int64-as-int32-pairs vs int32 sniff (high words of non-neg int64 are 0)
    bool is64 = ((ei[1] | ei[3] | ei[5] | ei[7]) == 0);
    const int base = blockIdx.x * (N_EDGES / FLAG_BLOCKS);   // 6250 edges/block
    if (is64) {
        // col array at words [2E, 4E), stride-2; uint4 = 2 edges. Alignment:
        // 4*(2E + 2*base) % 16 == 0 since base % 2 == 0.
        const uint4* p = (const uint4*)(ei + 2 * N_EDGES + 2 * base);
        for (int t = threadIdx.x; t < 3125; t += 256) {
            uint4 v = p[t];
            atomicOr(&lbm[v.x >> 5], 1u << (v.x & 31));
            atomicOr(&lbm[v.z >> 5], 1u << (v.z & 31));
        }
    } else {
        const uint2* p = (const uint2*)(ei + N_EDGES + base);  // base even -> 8B-aligned
        for (int t = threadIdx.x; t < 3125; t += 256) {
            uint2 v = p[t];
            atomicOr(&lbm[v.x >> 5], 1u << (v.x & 31));
            atomicOr(&lbm[v.y >> 5], 1u << (v.y & 31));
        }
    }
    __syncthreads();

    unsigned int* dst = parts + (size_t)blockIdx.x * PART_STRIDE;
    for (int i = threadIdx.x; i < BM_WORDS; i += 256) dst[i] = lbm[i];
}

// out[n,:] = hasedge[n] ? (x @ W)[n,:] : 0.  fp32 in, bf16 MFMA, fp32 store.
// 128 rows/block, 2 blocks/CU. Both operands staged to LDS:
//   - W transposed once per block (L2-resident, cheap)
//   - A (x rows) streamed with fully-coalesced float4 loads -> bf16 ds_write,
//     replacing the previous 64-way-scattered per-lane fragment gathers.
// flag_reduce is folded in: each block ORs the 256 partial masks for its own
// 4 mask words (one wave-shfl reduce), saving a kernel launch + gbm traffic.
__global__ __launch_bounds__(256, 2)
void gemm_fused(const float* __restrict__ xf,
                const float* __restrict__ wf,
                const unsigned int* __restrict__ parts,
                float* __restrict__ out) {
    __shared__ __attribute__((aligned(16))) unsigned short ldsW[N_DIM * LDA];
    __shared__ __attribute__((aligned(16))) unsigned short ldsA[BROWS * LDA];
    __shared__ unsigned int lmask[4][4];     // [contrib wave][mask word]

    const int tid  = threadIdx.x;
    const int lane = tid & 63;
    const int wave = tid >> 6;
    const int rb0  = blockIdx.x * BROWS;

    // ---- inline flag-reduce: OR the 256 partials' 4 words for this block.
    // thread b reads partial b (uint4, coalesced across the partial stride),
    // wave-level OR-reduce, 4 wave results combined at the epilogue.
    {
        const unsigned int* p =
            parts + (size_t)tid * PART_STRIDE + blockIdx.x * 4;
        uint4 pv = *(const uint4*)p;   // words 4b..4b+3 (< PART_STRIDE, safe)
#pragma unroll
        for (int off = 32; off; off >>= 1) {
            pv.x |= __shfl_xor(pv.x, off);
            pv.y |= __shfl_xor(pv.y, off);
            pv.z |= __shfl_xor(pv.z, off);
            pv.w |= __shfl_xor(pv.w, off);
        }
        if (lane == 0) {
            lmask[wave][0] = pv.x; lmask[wave][1] = pv.y;
            lmask[wave][2] = pv.z; lmask[wave][3] = pv.w;
        }
    }

    // ---- stage W (transpose-read, coalesced along n; conflict-free ds_write)
#pragma unroll
    for (int i = 0; i < 8; ++i) {
        int c  = i * 256 + tid;           // 0..2047
        int n  = c & 127;
        int k0 = (c >> 7) << 3;           // 0,8,...,120
        unsigned short tmp[8];
#pragma unroll
        for (int j = 0; j < 8; ++j) tmp[j] = f2bf(wf[(k0 + j) * N_DIM + n]);
        *(uint4*)(ldsW + n * LDA + k0) = *(const uint4*)tmp;
    }

    // ---- stage A: 128 rows x 128 k, fully coalesced float4 stream.
    // 32 consecutive lanes sweep one row (512B contiguous per half-wave).
#pragma unroll
    for (int i = 0; i < 16; ++i) {
        int f  = i * 256 + tid;           // float4 index 0..4095
        int rl = f >> 5;                  // local row 0..127
        int c4 = f & 31;                  // float4 column 0..31
        int rg = rb0 + rl;
        if (rg >= N_NODES) rg = N_NODES - 1;          // clamp: loads stay safe
        f32x4 v = *(const f32x4*)(xf + (size_t)rg * K_DIM + c4 * 4);
        unsigned short t4[4];
#pragma unroll
        for (int j = 0; j < 4; ++j) t4[j] = f2bf(v[j]);
        *(uint2*)(ldsA + rl * LDA + c4 * 4) = *(const uint2*)t4;  // 8B, 2-way free
    }
    __syncthreads();

    const int m    = lane & 15;   // A row / B col / C col
    const int quad = lane >> 4;   // 0..3
    const int rowb = wave * 32;   // wave's first local row (32 rows/wave)

    f32x4 acc[2][8];
#pragma unroll
    for (int mt = 0; mt < 2; ++mt)
#pragma unroll
        for (int t = 0; t < 8; ++t) acc[mt][t] = (f32x4){0.f, 0.f, 0.f, 0.f};

#pragma unroll
    for (int kk = 0; kk < 4; ++kk) {
        const int kbase = kk * 32 + quad * 8;
        bf16x8 af[2];
#pragma unroll
        for (int mt = 0; mt < 2; ++mt)
            af[mt] = *(const bf16x8*)(ldsA + (rowb + mt * 16 + m) * LDA + kbase);
#pragma unroll
        for (int t = 0; t < 8; ++t) {
            bf16x8 bfrag = *(const bf16x8*)(ldsW + (t * 16 + m) * LDA + kbase);
#pragma unroll
            for (int mt = 0; mt < 2; ++mt)
                acc[mt][t] = __builtin_amdgcn_mfma_f32_16x16x32_bf16(
                    af[mt], bfrag, acc[mt][t], 0, 0, 0);
        }
    }

    // final mask word for this wave's 32 rows (local rows wave*32..wave*32+31)
    const unsigned int fm = lmask[0][wave] | lmask[1][wave] |
                            lmask[2][wave] | lmask[3][wave];

    // C/D layout: col = lane&15, row = quad*4 + reg
#pragma unroll
    for (int mt = 0; mt < 2; ++mt) {
#pragma unroll
        for (int r = 0; r < 4; ++r) {
            int lrow = rowb + mt * 16 + quad * 4 + r;
            int orow = rb0 + lrow;
            if (orow < N_NODES) {
                float fmul = ((fm >> (lrow & 31)) & 1) ? 1.0f : 0.0f;
#pragma unroll
                for (int t = 0; t < 8; ++t)
                    out[(size_t)orow * N_DIM + t * 16 + m] = acc[mt][t][r] * fmul;
            }
        }
    }
}

extern "C" void kernel_launch(void* const* d_in, const int* in_sizes, int n_in,
                              void* d_out, int out_size, void* d_ws, size_t ws_size,
                              hipStream_t stream) {
    const float* x = (const float*)d_in[0];
    const float* w = (const float*)d_in[1];
    // d_in[2] (att) is mathematically irrelevant: normalized attention weights
    // sum to s/(s+1e-16) == 1 per segment in fp32, and the reference
    // aggregates h[col]*alpha into col, so out[n] = h[n] (or 0 if no in-edge).
    const int* ei = (const int*)d_in[3];
    float* out = (float*)d_out;

    unsigned int* parts = (unsigned int*)d_ws + PART_OFF; // 256 partial masks

    flag_partial<<<FLAG_BLOCKS, 256, 0, stream>>>(ei, parts);
    gemm_fused<<<(N_NODES + BROWS - 1) / BROWS, 256, 0, stream>>>(x, w, parts, out);
}